// Round 4
// baseline (191.004 us; speedup 1.0000x reference)
//
#include <hip/hip_runtime.h>

#define IF 212445
#define N1 65536
#define N2 16384
#define NCLS 20
#define BATCH 32
#define HISTB 32
#define MCHUNK 1024
#define MBLK ((IF + MCHUNK - 1) / MCHUNK)     // 208
#define TCHUNK 2048
#define NCH ((IF + TCHUNK - 1) / TCHUNK)      // 104
#define TOTALB (8 * NCH)                       // 832 = 8 row-quads x 104 chunks

// ws layout (bytes, all 16B aligned):
#define OFF_T3   0        // float[32*128]  zeroed each call
#define OFF_DONE 16384    // int            zeroed each call
#define OFF_HIST 16400    // int[32*256]    per-block partials (written)
#define OFF_A    49168    // float[20*128]  A[cls,m] = sum_o fc_w*u2
#define OFF_SV   59408    // float[20*128]  Sv[cls,m] = sum_o fc_w*v2
#define OFF_SW   69648    // float[20*128]  Sw[cls,m] = sum_o fc_w*w2
#define OFF_CP   79888    // float[20]      fc_b + sum_m Sb
#define OFF_MIDX 79968    // int[IF]        composed parent chain

// Launch 1: 261 blocks.
//  b < 208          : midx[i] = p2[p1[p0[i]]] (int4 vectorized)
//  b == 208         : zero t3 + done
//  b in [209,241)   : count-histogram partials (c2 over N1 chain, cnt2 over N2)
//  b in [241,261)   : per-class A/Sv/Sw/constP from fc_w (redundant tiny chain)
__global__ __launch_bounds__(256) void k_setup(
    const float* __restrict__ W0, const float* __restrict__ b0,
    const float* __restrict__ W1, const float* __restrict__ b1,
    const float* __restrict__ W2, const float* __restrict__ b2,
    const float* __restrict__ fc_w, const float* __restrict__ fc_b,
    const int* __restrict__ p0, const int* __restrict__ p1,
    const int* __restrict__ p2, char* __restrict__ ws)
{
    int t = threadIdx.x, b = blockIdx.x;
    float* t3   = (float*)(ws + OFF_T3);
    int*   done = (int*)(ws + OFF_DONE);
    int*   hist = (int*)(ws + OFF_HIST);
    float* A    = (float*)(ws + OFF_A);
    float* Sv   = (float*)(ws + OFF_SV);
    float* Sw   = (float*)(ws + OFF_SW);
    float* CP   = (float*)(ws + OFF_CP);
    int*   midx = (int*)(ws + OFF_MIDX);

    if (b < MBLK) {
        int i = b * MCHUNK + 4 * t;
        if (i + 3 < IF) {
            int4 p = *(const int4*)(p0 + i);
            int4 r;
            r.x = p2[p1[p.x]]; r.y = p2[p1[p.y]];
            r.z = p2[p1[p.z]]; r.w = p2[p1[p.w]];
            *(int4*)(midx + i) = r;
        } else {
            for (int j = i; j < IF; ++j) midx[j] = p2[p1[p0[j]]];
        }
    } else if (b == MBLK) {
        for (int s = t; s < BATCH * 128; s += 256) t3[s] = 0.f;
        if (t == 0) *done = 0;
    } else if (b < MBLK + 1 + HISTB) {
        int hb = b - (MBLK + 1);
        __shared__ int hA[128], hB[128];
        if (t < 128) { hA[t] = 0; hB[t] = 0; }
        __syncthreads();
        const int total = N1 + N2;
        for (int idx = hb * 256 + t; idx < total; idx += HISTB * 256) {
            if (idx < N1) atomicAdd(&hA[p2[p1[idx]]], 1);
            else          atomicAdd(&hB[p2[idx - N1]], 1);
        }
        __syncthreads();
        hist[hb * 256 + t] = (t < 128) ? hA[t] : hB[t - 128];
    } else {
        int cls = b - (MBLK + 1 + HISTB);
        __shared__ float su1[64], sv1[64];
        __shared__ float su2[128], sv2[128], sw2[128], sb2[128];
        __shared__ float pA[256], pV[256], pW[256], pB[256];
        if (t < 64) {
            float a = 0.f, bb = 0.f;
            for (int c = 0; c < 32; ++c) {
                float w = W1[t * 32 + c];
                a += w * W0[c]; bb += w * b0[c];   // W0 is (32,1)
            }
            su1[t] = a; sv1[t] = bb;
        }
        if (t >= 128) sb2[t - 128] = b2[t - 128];
        __syncthreads();
        if (t < 128) {
            float a = 0.f, bb = 0.f, c = 0.f;
            for (int j = 0; j < 64; ++j) {
                float w = W2[t * 64 + j];
                a += w * su1[j]; bb += w * sv1[j]; c += w * b1[j];
            }
            su2[t] = a; sv2[t] = bb; sw2[t] = c;
        }
        __syncthreads();
        int m = t & 127, h = t >> 7;
        const float* fw = fc_w + cls * 16384 + m;
        float Sa = 0.f, SvA = 0.f, SwA = 0.f, SbA = 0.f;
        #pragma unroll 8
        for (int o = h * 64; o < h * 64 + 64; ++o) {
            float w = fw[o * 128];
            Sa += w * su2[o]; SvA += w * sv2[o];
            SwA += w * sw2[o]; SbA += w * sb2[o];
        }
        pA[t] = Sa; pV[t] = SvA; pW[t] = SwA; pB[t] = SbA;
        __syncthreads();
        if (t < 128) {
            A [cls * 128 + t] = pA[t] + pA[t + 128];
            Sv[cls * 128 + t] = pV[t] + pV[t + 128];
            Sw[cls * 128 + t] = pW[t] + pW[t + 128];
            pB[t] = pB[t] + pB[t + 128];
        }
        __syncthreads();
        for (int s2 = 64; s2 > 0; s2 >>= 1) {
            if (t < s2) pB[t] += pB[t + s2];
            __syncthreads();
        }
        if (t == 0) CP[cls] = fc_b[cls] + pB[0];
    }
}

// Launch 2: 832 blocks. Each block: 4 batch rows x 2048-leaf chunk into a
// shared 4x128 LDS histogram, flush to t3 with global atomics; the LAST
// block (completion counter) then computes the whole epilogue in-kernel.
__global__ __launch_bounds__(256) void k_main(
    const float* __restrict__ x, char* __restrict__ ws,
    float* __restrict__ out)
{
    __shared__ float smem[8192];   // 32 KB: 2 KB hist phase, reused by epilogue
    __shared__ int isLast;
    int t = threadIdx.x;
    float* t3   = (float*)(ws + OFF_T3);
    int*   done = (int*)(ws + OFF_DONE);
    const int*   hist = (const int*)(ws + OFF_HIST);
    const float* A    = (const float*)(ws + OFF_A);
    const float* Svt  = (const float*)(ws + OFF_SV);
    const float* Swt  = (const float*)(ws + OFF_SW);
    const float* CP   = (const float*)(ws + OFF_CP);
    const int*   midx = (const int*)(ws + OFF_MIDX);

    for (int s = t; s < 512; s += 256) smem[s] = 0.f;
    __syncthreads();

    int g = blockIdx.x & 7, chunk = blockIdx.x >> 3;
    int r0 = g * 4, base = chunk * TCHUNK;
    const float* x0 = x + (size_t)(r0 + 0) * IF;
    const float* x1 = x + (size_t)(r0 + 1) * IF;
    const float* x2 = x + (size_t)(r0 + 2) * IF;
    const float* x3 = x + (size_t)(r0 + 3) * IF;
    int iend = base + TCHUNK; if (iend > IF) iend = IF;

    #pragma unroll 2
    for (int i = base + t; i < iend; i += 256) {
        int m = midx[i];
        float v0 = x0[i], v1 = x1[i], v2 = x2[i], v3 = x3[i];
        atomicAdd(&smem[      m], v0);
        atomicAdd(&smem[128 + m], v1);
        atomicAdd(&smem[256 + m], v2);
        atomicAdd(&smem[384 + m], v3);
    }
    __syncthreads();
    {
        int s0 = t, s1 = t + 256;
        atomicAdd(&t3[(r0 + (s0 >> 7)) * 128 + (s0 & 127)], smem[s0]);
        atomicAdd(&t3[(r0 + (s1 >> 7)) * 128 + (s1 & 127)], smem[s1]);
    }
    __threadfence();
    if (t == 0) isLast = (atomicAdd(done, 1) == TOTALB - 1) ? 1 : 0;
    __syncthreads();
    if (!isLast) return;
    __threadfence();

    // ---- epilogue (single block) ----
    float* st3   = smem;          // [m*33 + n]   4224 floats (pad 33 vs banks)
    float* sA    = smem + 4224;   // [m*20 + cls] 2560
    float* c2f   = smem + 6784;   // 128
    float* cnf   = smem + 6912;   // 128
    float* cpart = smem + 7040;   // 160
    float* scst  = smem + 7200;   // 20

    #pragma unroll
    for (int k = 0; k < 16; ++k) {
        int s = t + 256 * k;
        float v = __hip_atomic_load(&t3[s], __ATOMIC_RELAXED,
                                    __HIP_MEMORY_SCOPE_AGENT);
        st3[(s & 127) * 33 + (s >> 7)] = v;
    }
    #pragma unroll
    for (int k = 0; k < 10; ++k) {
        int q = t + 256 * k;
        sA[(q & 127) * 20 + (q >> 7)] = A[q];
    }
    {
        int acc = 0;
        #pragma unroll
        for (int h = 0; h < HISTB; ++h) acc += hist[h * 256 + t];
        if (t < 128) c2f[t] = (float)acc; else cnf[t - 128] = (float)acc;
    }
    __syncthreads();
    if (t < 160) {
        int cls = t >> 3, m0 = (t & 7) * 16;
        const float* sv = Svt + cls * 128;
        const float* sw = Swt + cls * 128;
        float s = 0.f;
        #pragma unroll
        for (int m = m0; m < m0 + 16; ++m)
            s += c2f[m] * sv[m] + cnf[m] * sw[m];
        cpart[t] = s;
    }
    __syncthreads();
    if (t < NCLS) {
        float s = CP[t];
        #pragma unroll
        for (int k = 0; k < 8; ++k) s += cpart[t * 8 + k];
        scst[t] = s;
    }
    __syncthreads();
    #pragma unroll
    for (int k = 0; k < 3; ++k) {
        int p = t + 256 * k;
        if (p < BATCH * NCLS) {
            int n = p / NCLS, cls = p - n * NCLS;
            float acc = scst[cls];
            #pragma unroll 8
            for (int m = 0; m < 128; ++m)
                acc += sA[m * 20 + cls] * st3[m * 33 + n];
            out[p] = acc;
        }
    }
}

extern "C" void kernel_launch(void* const* d_in, const int* in_sizes, int n_in,
                              void* d_out, int out_size, void* d_ws, size_t ws_size,
                              hipStream_t stream)
{
    const float* x    = (const float*)d_in[0];
    const float* W0   = (const float*)d_in[1];
    const float* b0   = (const float*)d_in[2];
    const float* W1   = (const float*)d_in[3];
    const float* b1   = (const float*)d_in[4];
    const float* W2   = (const float*)d_in[5];
    const float* b2   = (const float*)d_in[6];
    const float* fc_w = (const float*)d_in[7];
    const float* fc_b = (const float*)d_in[8];
    const int*   p0   = (const int*)d_in[9];
    const int*   p1   = (const int*)d_in[10];
    const int*   p2   = (const int*)d_in[11];

    k_setup<<<MBLK + 1 + HISTB + NCLS, 256, 0, stream>>>(
        W0, b0, W1, b1, W2, b2, fc_w, fc_b, p0, p1, p2, (char*)d_ws);
    k_main<<<TOTALB, 256, 0, stream>>>(x, (char*)d_ws, (float*)d_out);
}

// Round 6
// 142.677 us; speedup vs baseline: 1.3387x; 1.3387x over previous
//
#include <hip/hip_runtime.h>

#define IF 212445
#define N1 65536
#define N2 16384
#define NCLS 20
#define BATCH 32
#define HISTB 32
#define MCHUNK 1024
#define MBLK ((IF + MCHUNK - 1) / MCHUNK)     // 208
#define TCHUNK 2048
#define NCH ((IF + TCHUNK - 1) / TCHUNK)      // 104
#define TOTALB (8 * NCH)                       // 832 = 8 row-quads x 104 chunks

// ws layout (bytes, all 16B aligned):
#define OFF_T3   0        // float[32*128]  zeroed each call
#define OFF_DONE 16384    // int            zeroed each call
#define OFF_HIST 16400    // int[32*256]    per-block partials (written)
#define OFF_A    49168    // float[20*128]
#define OFF_SV   59408    // float[20*128]
#define OFF_SW   69648    // float[20*128]
#define OFF_CP   79888    // float[20]
#define OFF_MIDX 79968    // int[IF]

// Launch 1: 261 blocks (identical to R4 — it was never the bottleneck).
__global__ __launch_bounds__(256) void k_setup(
    const float* __restrict__ W0, const float* __restrict__ b0,
    const float* __restrict__ W1, const float* __restrict__ b1,
    const float* __restrict__ W2, const float* __restrict__ b2,
    const float* __restrict__ fc_w, const float* __restrict__ fc_b,
    const int* __restrict__ p0, const int* __restrict__ p1,
    const int* __restrict__ p2, char* __restrict__ ws)
{
    int t = threadIdx.x, b = blockIdx.x;
    float* t3   = (float*)(ws + OFF_T3);
    int*   done = (int*)(ws + OFF_DONE);
    int*   hist = (int*)(ws + OFF_HIST);
    float* A    = (float*)(ws + OFF_A);
    float* Sv   = (float*)(ws + OFF_SV);
    float* Sw   = (float*)(ws + OFF_SW);
    float* CP   = (float*)(ws + OFF_CP);
    int*   midx = (int*)(ws + OFF_MIDX);

    if (b < MBLK) {
        int i = b * MCHUNK + 4 * t;
        if (i + 3 < IF) {
            int4 p = *(const int4*)(p0 + i);
            int4 r;
            r.x = p2[p1[p.x]]; r.y = p2[p1[p.y]];
            r.z = p2[p1[p.z]]; r.w = p2[p1[p.w]];
            *(int4*)(midx + i) = r;
        } else {
            for (int j = i; j < IF; ++j) midx[j] = p2[p1[p0[j]]];
        }
    } else if (b == MBLK) {
        for (int s = t; s < BATCH * 128; s += 256) t3[s] = 0.f;
        if (t == 0) *done = 0;
    } else if (b < MBLK + 1 + HISTB) {
        int hb = b - (MBLK + 1);
        __shared__ int hA[128], hB[128];
        if (t < 128) { hA[t] = 0; hB[t] = 0; }
        __syncthreads();
        const int total = N1 + N2;
        for (int idx = hb * 256 + t; idx < total; idx += HISTB * 256) {
            if (idx < N1) atomicAdd(&hA[p2[p1[idx]]], 1);
            else          atomicAdd(&hB[p2[idx - N1]], 1);
        }
        __syncthreads();
        hist[hb * 256 + t] = (t < 128) ? hA[t] : hB[t - 128];
    } else {
        int cls = b - (MBLK + 1 + HISTB);
        __shared__ float su1[64], sv1[64];
        __shared__ float su2[128], sv2[128], sw2[128], sb2[128];
        __shared__ float pA[256], pV[256], pW[256], pB[256];
        if (t < 64) {
            float a = 0.f, bb = 0.f;
            for (int c = 0; c < 32; ++c) {
                float w = W1[t * 32 + c];
                a += w * W0[c]; bb += w * b0[c];   // W0 is (32,1)
            }
            su1[t] = a; sv1[t] = bb;
        }
        if (t >= 128) sb2[t - 128] = b2[t - 128];
        __syncthreads();
        if (t < 128) {
            float a = 0.f, bb = 0.f, c = 0.f;
            for (int j = 0; j < 64; ++j) {
                float w = W2[t * 64 + j];
                a += w * su1[j]; bb += w * sv1[j]; c += w * b1[j];
            }
            su2[t] = a; sv2[t] = bb; sw2[t] = c;
        }
        __syncthreads();
        int m = t & 127, h = t >> 7;
        const float* fw = fc_w + cls * 16384 + m;
        float Sa = 0.f, SvA = 0.f, SwA = 0.f, SbA = 0.f;
        #pragma unroll 8
        for (int o = h * 64; o < h * 64 + 64; ++o) {
            float w = fw[o * 128];
            Sa += w * su2[o]; SvA += w * sv2[o];
            SwA += w * sw2[o]; SbA += w * sb2[o];
        }
        pA[t] = Sa; pV[t] = SvA; pW[t] = SwA; pB[t] = SbA;
        __syncthreads();
        if (t < 128) {
            A [cls * 128 + t] = pA[t] + pA[t + 128];
            Sv[cls * 128 + t] = pV[t] + pV[t + 128];
            Sw[cls * 128 + t] = pW[t] + pW[t + 128];
            pB[t] = pB[t] + pB[t + 128];
        }
        __syncthreads();
        for (int s2 = 64; s2 > 0; s2 >>= 1) {
            if (t < s2) pB[t] += pB[t + s2];
            __syncthreads();
        }
        if (t == 0) CP[cls] = fc_b[cls] + pB[0];
    }
}

// Launch 2: 832 blocks, NO device fences in the hot path.
// Wave-private per-row LDS histograms; flush with device-scope atomics;
// __syncthreads() provides the vmcnt(0) drain (compiler-guaranteed) so a
// relaxed done-counter increment after the barrier is a free release.
// Only the single last block pays one acquire fence, then runs the epilogue.
__global__ __launch_bounds__(256) void k_main(
    const float* __restrict__ x, char* __restrict__ ws,
    float* __restrict__ out)
{
    __shared__ float smem[8192];   // 32 KB; [0,2048) = 4 waves x 4 rows x 128 bins
    __shared__ int isLast;
    int t = threadIdx.x;
    float* t3   = (float*)(ws + OFF_T3);
    int*   done = (int*)(ws + OFF_DONE);
    const int*   hist = (const int*)(ws + OFF_HIST);
    const float* A    = (const float*)(ws + OFF_A);
    const float* Svt  = (const float*)(ws + OFF_SV);
    const float* Swt  = (const float*)(ws + OFF_SW);
    const float* CP   = (const float*)(ws + OFF_CP);
    const int*   midx = (const int*)(ws + OFF_MIDX);

    for (int s = t; s < 2048; s += 256) smem[s] = 0.f;
    __syncthreads();

    int g = blockIdx.x & 7, chunk = blockIdx.x >> 3;
    int r0 = g * 4, base = chunk * TCHUNK;
    const float* x0 = x + (size_t)(r0 + 0) * IF;
    const float* x1 = x + (size_t)(r0 + 1) * IF;
    const float* x2 = x + (size_t)(r0 + 2) * IF;
    const float* x3 = x + (size_t)(r0 + 3) * IF;
    float* hw = smem + (t >> 6) * 512;   // this wave's private 4x128

    if (base + TCHUNK <= IF) {
        #pragma unroll 1
        for (int k = 0; k < TCHUNK / 1024; ++k) {   // 2 outer iters
            float v0[4], v1[4], v2[4], v3[4]; int mi[4];
            int i0 = base + k * 1024 + t;
            #pragma unroll
            for (int u = 0; u < 4; ++u) {
                int i = i0 + u * 256;
                mi[u] = midx[i];
                v0[u] = x0[i]; v1[u] = x1[i]; v2[u] = x2[i]; v3[u] = x3[i];
            }
            #pragma unroll
            for (int u = 0; u < 4; ++u) {
                atomicAdd(&hw[      mi[u]], v0[u]);
                atomicAdd(&hw[128 + mi[u]], v1[u]);
                atomicAdd(&hw[256 + mi[u]], v2[u]);
                atomicAdd(&hw[384 + mi[u]], v3[u]);
            }
        }
    } else {
        for (int i = base + t; i < IF; i += 256) {
            int m = midx[i];
            atomicAdd(&hw[      m], x0[i]);
            atomicAdd(&hw[128 + m], x1[i]);
            atomicAdd(&hw[256 + m], x2[i]);
            atomicAdd(&hw[384 + m], x3[i]);
        }
    }
    __syncthreads();
    // reduce the 4 wave-copies and flush (device-scope atomics -> coherent point)
    for (int s = t; s < 512; s += 256) {
        float v = smem[s] + smem[512 + s] + smem[1024 + s] + smem[1536 + s];
        atomicAdd(&t3[(r0 + (s >> 7)) * 128 + (s & 127)], v);
    }
    __syncthreads();   // compiler emits s_waitcnt vmcnt(0) before s_barrier:
                       // all our t3 atomics have reached the coherent point.
    if (t == 0) isLast = (atomicAdd(done, 1) == TOTALB - 1) ? 1 : 0;
    __syncthreads();
    if (!isLast) return;
    __builtin_amdgcn_fence(__ATOMIC_ACQUIRE, "agent");

    // ---- epilogue (single block) ----
    float* st3   = smem;          // [m*33 + n]   4224 floats
    float* sA    = smem + 4224;   // [m*20 + cls] 2560
    float* c2f   = smem + 6784;   // 128
    float* cnf   = smem + 6912;   // 128
    float* cpart = smem + 7040;   // 160
    float* scst  = smem + 7200;   // 20
    __syncthreads();              // everyone done with hist region

    #pragma unroll
    for (int k = 0; k < 16; ++k) {
        int s = t + 256 * k;
        st3[(s & 127) * 33 + (s >> 7)] = t3[s];
    }
    #pragma unroll
    for (int k = 0; k < 10; ++k) {
        int q = t + 256 * k;
        sA[(q & 127) * 20 + (q >> 7)] = A[q];
    }
    {
        int acc = 0;
        #pragma unroll
        for (int h = 0; h < HISTB; ++h) acc += hist[h * 256 + t];
        if (t < 128) c2f[t] = (float)acc; else cnf[t - 128] = (float)acc;
    }
    __syncthreads();
    if (t < 160) {
        int cls = t >> 3, m0 = (t & 7) * 16;
        const float* sv = Svt + cls * 128;
        const float* sw = Swt + cls * 128;
        float s = 0.f;
        #pragma unroll
        for (int m = m0; m < m0 + 16; ++m)
            s += c2f[m] * sv[m] + cnf[m] * sw[m];
        cpart[t] = s;
    }
    __syncthreads();
    if (t < NCLS) {
        float s = CP[t];
        #pragma unroll
        for (int k = 0; k < 8; ++k) s += cpart[t * 8 + k];
        scst[t] = s;
    }
    __syncthreads();
    #pragma unroll
    for (int k = 0; k < 3; ++k) {
        int p = t + 256 * k;
        if (p < BATCH * NCLS) {
            int n = p / NCLS, cls = p - n * NCLS;
            float acc = scst[cls];
            #pragma unroll 8
            for (int m = 0; m < 128; ++m)
                acc += sA[m * 20 + cls] * st3[m * 33 + n];
            out[p] = acc;
        }
    }
}

extern "C" void kernel_launch(void* const* d_in, const int* in_sizes, int n_in,
                              void* d_out, int out_size, void* d_ws, size_t ws_size,
                              hipStream_t stream)
{
    const float* x    = (const float*)d_in[0];
    const float* W0   = (const float*)d_in[1];
    const float* b0   = (const float*)d_in[2];
    const float* W1   = (const float*)d_in[3];
    const float* b1   = (const float*)d_in[4];
    const float* W2   = (const float*)d_in[5];
    const float* b2   = (const float*)d_in[6];
    const float* fc_w = (const float*)d_in[7];
    const float* fc_b = (const float*)d_in[8];
    const int*   p0   = (const int*)d_in[9];
    const int*   p1   = (const int*)d_in[10];
    const int*   p2   = (const int*)d_in[11];

    k_setup<<<MBLK + 1 + HISTB + NCLS, 256, 0, stream>>>(
        W0, b0, W1, b1, W2, b2, fc_w, fc_b, p0, p1, p2, (char*)d_ws);
    k_main<<<TOTALB, 256, 0, stream>>>(x, (char*)d_ws, (float*)d_out);
}